// Round 1
// 180.361 us; speedup vs baseline: 1.1897x; 1.1897x over previous
//
#include <hip/hip_runtime.h>
#include <hip/hip_fp16.h>

#define N_NODES 50000
#define N_EDGES 800000
#define N_GRAPHS 256
#define NCB 196        // coarse buckets = ceil(50000/256), dst>>8
#define CHUNK 3125     // edges per block in coarse passes (256 blocks)
#define MBLK 782       // ceil(50000/64)

typedef _Float16 f16x8 __attribute__((ext_vector_type(8)));
typedef float    f32x4 __attribute__((ext_vector_type(4)));

// ---------------------------------------------------------------------------
// hist_prep: blocks 0..255 coarse edge histogram (dst>>8); blocks 256..6813
// independent prep (pad XPh, bounds, fp16 fragment-packed weights).
// ---------------------------------------------------------------------------
__global__ __launch_bounds__(256)
void hist_prep(const int* __restrict__ ER, const float* __restrict__ X,
               const int* __restrict__ SEG,
               const float* __restrict__ W1, const float* __restrict__ W2,
               const float* __restrict__ W12, const float* __restrict__ W22,
               const float* __restrict__ W13, const float* __restrict__ W23,
               int* __restrict__ ghist, __half* __restrict__ XPh,
               int* __restrict__ start,
               __half* __restrict__ W1f, __half* __restrict__ W2f,
               __half* __restrict__ W3f)
{
    int b = blockIdx.x;
    int t = threadIdx.x;
    if (b < 256) {                           // coarse histogram
        __shared__ int h[NCB];
        for (int i = t; i < NCB; i += 256) h[i] = 0;
        __syncthreads();
        int lo = b * CHUNK, hi = lo + CHUNK;
        for (int e = lo + t; e < hi; e += 256) atomicAdd(&h[ER[e] >> 8], 1);
        __syncthreads();
        for (int i = t; i < NCB; i += 256) ghist[i * 256 + b] = h[i];
        return;
    }
    int bid = b - 256;
    if (bid < 6250) {                        // pad: XPh fp16 (dense12 X-half)
        int idx = bid * 256 + t;
        int n = idx >> 5;
        int c = idx & 31;
        float v = (c < 30) ? X[n * 30 + c] : 0.f;
        XPh[(size_t)n * 32 + c] = __float2half(v);
    } else if (bid < 6446) {                 // bounds from sorted seg
        int n = (bid - 6250) * 256 + t;
        if (n >= N_NODES) return;
        int g = SEG[n];
        int gprev = (n == 0) ? -1 : SEG[n - 1];
        for (int gg = gprev + 1; gg <= g; ++gg) start[gg] = n;
        if (n == N_NODES - 1)
            for (int gg = g + 1; gg <= N_GRAPHS; ++gg) start[gg] = N_NODES;
    } else {                                 // fragment-packed fp16 weights
        int idx = (bid - 6446) * 256 + t;    // 0 .. 28671
        if (idx < 8192) {                    // W1f: 64x128 ([W1_1;pad;W2_1])
            int i = idx & 7, c = (idx >> 3) & 15, g = (idx >> 7) & 3;
            int s = (idx >> 9) & 1, n = idx >> 10;
            int k = s * 32 + g * 8 + i, col = n * 16 + c;
            float w = 0.f;
            if (k < 30) w = W1[k * 128 + col];
            else if (k >= 32 && k < 62) w = W2[(k - 32) * 128 + col];
            W1f[idx] = __float2half(w);
        } else if (idx < 24576) {            // W2f: 128x128 ([W1_2|W2_2])
            int o = idx - 8192;
            int i = o & 7, c = (o >> 3) & 15, g = (o >> 7) & 3;
            int s = (o >> 9) & 3, n = o >> 11;
            int k = s * 32 + g * 8 + i, col = n * 16 + c;
            float w = (col < 64) ? W12[k * 64 + col] : W22[k * 64 + col - 64];
            W2f[o] = __float2half(w);
        } else {                             // W3f: 64x64 ([W1_3|W2_3])
            int o = idx - 24576;
            int i = o & 7, c = (o >> 3) & 15, g = (o >> 7) & 3;
            int s = (o >> 9) & 1, n = o >> 10;
            int k = s * 32 + g * 8 + i, col = n * 16 + c;
            float w = (col < 32) ? W13[k * 32 + col] : W23[k * 32 + col - 32];
            W3f[o] = __float2half(w);
        }
    }
}

// ---------------------------------------------------------------------------
// scan1: per-bucket exclusive scan of the 256 per-block counts, in place;
// bucket total -> bsum[b].
// ---------------------------------------------------------------------------
__global__ __launch_bounds__(256)
void scan1(int* __restrict__ ghist, int* __restrict__ bsum)
{
    __shared__ int s[256];
    int t = threadIdx.x, b = blockIdx.x;
    int i = b * 256 + t;
    int v = ghist[i];
    s[t] = v;
    __syncthreads();
    for (int off = 1; off < 256; off <<= 1) {
        int u = (t >= off) ? s[t - off] : 0;
        __syncthreads();
        s[t] += u;
        __syncthreads();
    }
    ghist[i] = s[t] - v;
    if (t == 255) bsum[b] = s[255];
}

// ---------------------------------------------------------------------------
// c_scatter: coarse scatter into per-block contiguous runs.
// tmp_sd = src | ((dst&255)<<16) (4B); tmp_w = fp16 weight (2B).
// ---------------------------------------------------------------------------
__global__ __launch_bounds__(256)
void c_scatter(const int* __restrict__ ER, const int* __restrict__ EC,
               const float* __restrict__ EW, const int* __restrict__ ghist,
               const int* __restrict__ bsum, unsigned int* __restrict__ tmp_sd,
               __half* __restrict__ tmp_w)
{
    __shared__ int s[256];
    __shared__ int cur[NCB];
    int t = threadIdx.x, blk = blockIdx.x;
    int v = (t < NCB) ? bsum[t] : 0;
    s[t] = v;
    __syncthreads();
    for (int off = 1; off < 256; off <<= 1) {
        int u = (t >= off) ? s[t - off] : 0;
        __syncthreads();
        s[t] += u;
        __syncthreads();
    }
    if (t < NCB) cur[t] = (s[t] - v) + ghist[t * 256 + blk];
    __syncthreads();
    int lo = blk * CHUNK, hi = lo + CHUNK;
    for (int e = lo + t; e < hi; e += 256) {
        int d = ER[e];
        int pos = atomicAdd(&cur[d >> 8], 1);
        tmp_sd[pos] = (unsigned int)EC[e] | ((unsigned int)(d & 255) << 16);
        tmp_w[pos] = __float2half(EW[e]);
    }
}

// ---------------------------------------------------------------------------
// fp16 gather helper
// ---------------------------------------------------------------------------
__device__ __forceinline__ void fma8h(float4& a0, float4& a1, float w,
                                      const uint4& raw)
{
    const __half2* hp = (const __half2*)&raw;
    float2 f0 = __half22float2(hp[0]);
    float2 f1 = __half22float2(hp[1]);
    float2 f2 = __half22float2(hp[2]);
    float2 f3 = __half22float2(hp[3]);
    a0.x = fmaf(w, f0.x, a0.x); a0.y = fmaf(w, f0.y, a0.y);
    a0.z = fmaf(w, f1.x, a0.z); a0.w = fmaf(w, f1.y, a0.w);
    a1.x = fmaf(w, f2.x, a1.x); a1.y = fmaf(w, f2.y, a1.y);
    a1.z = fmaf(w, f3.x, a1.z); a1.w = fmaf(w, f3.y, a1.w);
}

__device__ __forceinline__ unsigned int relu2(unsigned int u)
{
    unsigned int lo = (u & 0x8000u)     ? 0u : (u & 0x0000FFFFu);
    unsigned int hi = (u & 0x80000000u) ? 0u : (u & 0xFFFF0000u);
    return lo | hi;
}

// ---------------------------------------------------------------------------
// bsort_aggx (512 thr): per-bucket counting sort -> packed + rowptr, then the
// same block does layer-1 aggx for its own 256 nodes (packed L1/L2-hot).
// ---------------------------------------------------------------------------
__global__ __launch_bounds__(512)
void bsort_aggx(const unsigned int* __restrict__ tmp_sd, const __half* __restrict__ tmp_w,
                const int* __restrict__ bsum, const __half* __restrict__ XPh,
                unsigned int* __restrict__ packed, int* __restrict__ rowptr,
                __half* __restrict__ CIa)
{
    __shared__ int s[256];
    __shared__ int hist[256];
    __shared__ int cur[256];
    __shared__ int r0arr[257];
    int t = threadIdx.x, b = blockIdx.x;

    if (t < 256) s[t] = (t < NCB) ? bsum[t] : 0;
    __syncthreads();
    for (int off = 1; off < 256; off <<= 1) {
        int u = 0;
        if (t < 256 && t >= off) u = s[t - off];
        __syncthreads();
        if (t < 256) s[t] += u;
        __syncthreads();
    }
    int cntb = bsum[b];
    int base = s[b] - cntb;
    int end  = base + cntb;
    __syncthreads();

    if (t < 256) hist[t] = 0;
    __syncthreads();
    for (int j = base + t; j < end; j += 512)
        atomicAdd(&hist[(tmp_sd[j] >> 16) & 255], 1);
    __syncthreads();
    int hv = 0;
    if (t < 256) { hv = hist[t]; s[t] = hv; }
    __syncthreads();
    for (int off = 1; off < 256; off <<= 1) {
        int u = 0;
        if (t < 256 && t >= off) u = s[t - off];
        __syncthreads();
        if (t < 256) s[t] += u;
        __syncthreads();
    }
    if (t < 256) {
        int excl = s[t] - hv;
        int n = b * 256 + t;
        if (n < N_NODES) rowptr[n] = base + excl;
        if (b == NCB - 1 && t == 0) rowptr[N_NODES] = N_EDGES;
        r0arr[t] = base + excl;
        cur[t] = base + excl;
        if (t == 0) r0arr[256] = end;
    }
    __syncthreads();
    for (int j = base + t; j < end; j += 512) {
        unsigned int sd = tmp_sd[j];
        unsigned short hb = __half_as_ushort(tmp_w[j]);
        int pos = atomicAdd(&cur[(sd >> 16) & 255], 1);
        packed[pos] = (sd & 0xFFFF) | ((unsigned int)hb << 16);
    }
    __syncthreads();   // packed writes drained

    // aggx: 4 lanes/node, 128 nodes/pass, 2 passes; unroll-4 gather.
    #pragma unroll
    for (int pass = 0; pass < 2; ++pass) {
        int local = pass * 128 + (t >> 2);
        int q = t & 3;
        int n = b * 256 + local;
        if (n < N_NODES) {
            int r0 = r0arr[local], r1 = r0arr[local + 1];
            float4 acc0 = make_float4(0.f, 0.f, 0.f, 0.f);
            float4 acc1 = make_float4(0.f, 0.f, 0.f, 0.f);
            int j = r0;
            for (; j + 3 < r1; j += 4) {
                unsigned int ra = packed[j],     rb = packed[j + 1];
                unsigned int rc = packed[j + 2], rd = packed[j + 3];
                uint4 rawa = *(const uint4*)(XPh + (size_t)(ra & 0xFFFF) * 32 + q * 8);
                uint4 rawb = *(const uint4*)(XPh + (size_t)(rb & 0xFFFF) * 32 + q * 8);
                uint4 rawc = *(const uint4*)(XPh + (size_t)(rc & 0xFFFF) * 32 + q * 8);
                uint4 rawd = *(const uint4*)(XPh + (size_t)(rd & 0xFFFF) * 32 + q * 8);
                float wa = __half2float(__ushort_as_half((unsigned short)(ra >> 16)));
                float wb = __half2float(__ushort_as_half((unsigned short)(rb >> 16)));
                float wc = __half2float(__ushort_as_half((unsigned short)(rc >> 16)));
                float wd = __half2float(__ushort_as_half((unsigned short)(rd >> 16)));
                fma8h(acc0, acc1, wa, rawa);
                fma8h(acc0, acc1, wb, rawb);
                fma8h(acc0, acc1, wc, rawc);
                fma8h(acc0, acc1, wd, rawd);
            }
            for (; j < r1; ++j) {
                unsigned int r = packed[j];
                uint4 raw = *(const uint4*)(XPh + (size_t)(r & 0xFFFF) * 32 + q * 8);
                float w = __half2float(__ushort_as_half((unsigned short)(r >> 16)));
                fma8h(acc0, acc1, w, raw);
            }
            __half2 hb2[4];
            hb2[0] = __float22half2_rn(make_float2(acc0.x, acc0.y));
            hb2[1] = __float22half2_rn(make_float2(acc0.z, acc0.w));
            hb2[2] = __float22half2_rn(make_float2(acc1.x, acc1.y));
            hb2[3] = __float22half2_rn(make_float2(acc1.z, acc1.w));
            *(uint4*)(CIa + (size_t)n * 32 + q * 8) = *(uint4*)&hb2[0];
        }
    }
}

// ---------------------------------------------------------------------------
// dense12_mfma: FUSED layers 1+2 on matrix cores.
// Phase A: [CIa|XPh](64x64 f16) @ W1f(64x128 f16) + b1 -> relu -> h1 (LDS f16)
// Phase B: h1(64x128) @ W2f(128x128) -> H2h (cols 0-63), A2h+b2 (cols 64-127)
// 4 waves; wave w owns output n-subtiles {2w, 2w+1}. Weights pre-packed in
// fragment order so B-frags are coalesced 16B/lane global loads (L1-hot).
// MFMA C/D mapping: col=lane&15, row=(lane>>4)*4+reg (HW-verified).
// ---------------------------------------------------------------------------
__global__ __launch_bounds__(256)
void dense12_mfma(const __half* __restrict__ CIa, const __half* __restrict__ XPh,
                  const __half* __restrict__ W1f, const float* __restrict__ B1,
                  const __half* __restrict__ W2f, const float* __restrict__ B2,
                  __half* __restrict__ H2h, __half* __restrict__ A2h)
{
    __shared__ __align__(16) __half As[64 * 72];    // input tile, stride 72
    __shared__ __align__(16) __half Hs[64 * 136];   // h1 tile / output tile
    const int tid = threadIdx.x;
    const int m0 = blockIdx.x * 64;
    const int lane = tid & 63;
    const int w  = tid >> 6;     // wave 0..3
    const int lr = lane & 15;    // frag row (A) / col (B,D)
    const int lg = lane >> 4;    // k-group / D-row-group

    // stage A: 64 rows x 64 halves  ([CIa | XPh])
    for (int idx = tid; idx < 512; idx += 256) {
        int row = idx >> 3, c8 = idx & 7;
        int gm = m0 + row;
        uint4 v = make_uint4(0, 0, 0, 0);
        if (gm < N_NODES) {
            const __half* src = (c8 < 4) ? (CIa + (size_t)gm * 32 + c8 * 8)
                                         : (XPh + (size_t)gm * 32 + (c8 - 4) * 8);
            v = *(const uint4*)src;
        }
        *(uint4*)(As + row * 72 + c8 * 8) = v;
    }
    __syncthreads();

    // phase A: K=64 (2 MFMA K-slices), 16 MFMAs/wave
    f32x4 acc[4][2];
    #pragma unroll
    for (int m = 0; m < 4; ++m)
        #pragma unroll
        for (int j = 0; j < 2; ++j)
            acc[m][j] = (f32x4){0.f, 0.f, 0.f, 0.f};

    #pragma unroll
    for (int s = 0; s < 2; ++s) {
        f16x8 a[4];
        #pragma unroll
        for (int m = 0; m < 4; ++m)
            a[m] = *(const f16x8*)(As + (m * 16 + lr) * 72 + s * 32 + lg * 8);
        #pragma unroll
        for (int j = 0; j < 2; ++j) {
            const int n = 2 * w + j;
            f16x8 b = *(const f16x8*)(W1f + (((n * 2 + s) * 4 + lg) * 16 + lr) * 8);
            #pragma unroll
            for (int m = 0; m < 4; ++m)
                acc[m][j] = __builtin_amdgcn_mfma_f32_16x16x32_f16(a[m], b, acc[m][j], 0, 0, 0);
        }
    }

    // +b1, relu, h1 -> LDS fp16
    #pragma unroll
    for (int j = 0; j < 2; ++j) {
        const int n = 2 * w + j;
        const float bias = B1[n * 16 + lr];
        #pragma unroll
        for (int m = 0; m < 4; ++m)
            #pragma unroll
            for (int r = 0; r < 4; ++r) {
                float v = fmaxf(acc[m][j][r] + bias, 0.f);
                Hs[(m * 16 + lg * 4 + r) * 136 + n * 16 + lr] = __float2half(v);
            }
    }
    __syncthreads();

    // phase B: K=128 (4 slices), 32 MFMAs/wave
    f32x4 acc2[4][2];
    #pragma unroll
    for (int m = 0; m < 4; ++m)
        #pragma unroll
        for (int j = 0; j < 2; ++j)
            acc2[m][j] = (f32x4){0.f, 0.f, 0.f, 0.f};

    #pragma unroll
    for (int s = 0; s < 4; ++s) {
        f16x8 a[4];
        #pragma unroll
        for (int m = 0; m < 4; ++m)
            a[m] = *(const f16x8*)(Hs + (m * 16 + lr) * 136 + s * 32 + lg * 8);
        #pragma unroll
        for (int j = 0; j < 2; ++j) {
            const int n = 2 * w + j;
            f16x8 b = *(const f16x8*)(W2f + (((n * 4 + s) * 4 + lg) * 16 + lr) * 8);
            #pragma unroll
            for (int m = 0; m < 4; ++m)
                acc2[m][j] = __builtin_amdgcn_mfma_f32_16x16x32_f16(a[m], b, acc2[m][j], 0, 0, 0);
        }
    }
    __syncthreads();   // all h1 reads done; Hs reusable for output

    #pragma unroll
    for (int j = 0; j < 2; ++j) {
        const int n = 2 * w + j;
        const float bias = (n >= 4) ? B2[(n - 4) * 16 + lr] : 0.f;
        #pragma unroll
        for (int m = 0; m < 4; ++m)
            #pragma unroll
            for (int r = 0; r < 4; ++r)
                Hs[(m * 16 + lg * 4 + r) * 136 + n * 16 + lr] =
                    __float2half(acc2[m][j][r] + bias);
    }
    __syncthreads();

    // coalesced fp16 store: cols 0-63 -> H2h, 64-127 -> A2h
    for (int idx = tid; idx < 1024; idx += 256) {
        int row = idx >> 4, c8 = idx & 15;
        int gm = m0 + row;
        if (gm < N_NODES) {
            uint4 v = *(const uint4*)(Hs + row * 136 + c8 * 8);
            if (c8 < 8) *(uint4*)(H2h + (size_t)gm * 64 + c8 * 8) = v;
            else        *(uint4*)(A2h + (size_t)gm * 64 + (c8 - 8) * 8) = v;
        }
    }
}

// ---------------------------------------------------------------------------
// dense3_mfma: relu(A2h)(64x64 f16) @ W3f(64x64 f16); wave w owns n-subtile w:
// n<2 -> H3h, n>=2 -> B2h (+b3). 8 MFMAs/wave.
// ---------------------------------------------------------------------------
__global__ __launch_bounds__(256)
void dense3_mfma(const __half* __restrict__ X, const __half* __restrict__ W3f,
                 const float* __restrict__ B3, __half* __restrict__ H3h,
                 __half* __restrict__ B2h)
{
    __shared__ __align__(16) __half As[64 * 72];
    __shared__ __align__(16) __half Os[64 * 72];
    const int tid = threadIdx.x;
    const int m0 = blockIdx.x * 64;
    const int lane = tid & 63;
    const int w  = tid >> 6;
    const int lr = lane & 15;
    const int lg = lane >> 4;

    for (int idx = tid; idx < 512; idx += 256) {
        int row = idx >> 3, c8 = idx & 7;
        int gm = m0 + row;
        uint4 v = make_uint4(0, 0, 0, 0);
        if (gm < N_NODES) v = *(const uint4*)(X + (size_t)gm * 64 + c8 * 8);
        v.x = relu2(v.x); v.y = relu2(v.y); v.z = relu2(v.z); v.w = relu2(v.w);
        *(uint4*)(As + row * 72 + c8 * 8) = v;
    }
    __syncthreads();

    f32x4 acc[4];
    #pragma unroll
    for (int m = 0; m < 4; ++m) acc[m] = (f32x4){0.f, 0.f, 0.f, 0.f};

    #pragma unroll
    for (int s = 0; s < 2; ++s) {
        f16x8 b = *(const f16x8*)(W3f + (((w * 2 + s) * 4 + lg) * 16 + lr) * 8);
        #pragma unroll
        for (int m = 0; m < 4; ++m) {
            f16x8 a = *(const f16x8*)(As + (m * 16 + lr) * 72 + s * 32 + lg * 8);
            acc[m] = __builtin_amdgcn_mfma_f32_16x16x32_f16(a, b, acc[m], 0, 0, 0);
        }
    }

    const float bias = (w >= 2) ? B3[(w - 2) * 16 + lr] : 0.f;
    #pragma unroll
    for (int m = 0; m < 4; ++m)
        #pragma unroll
        for (int r = 0; r < 4; ++r)
            Os[(m * 16 + lg * 4 + r) * 72 + w * 16 + lr] =
                __float2half(acc[m][r] + bias);
    __syncthreads();

    for (int idx = tid; idx < 512; idx += 256) {
        int row = idx >> 3, c8 = idx & 7;
        int gm = m0 + row;
        if (gm < N_NODES) {
            uint4 v = *(const uint4*)(Os + row * 72 + c8 * 8);
            if (c8 < 4) *(uint4*)(H3h + (size_t)gm * 32 + c8 * 8) = v;
            else        *(uint4*)(B2h + (size_t)gm * 32 + (c8 - 4) * 8) = v;
        }
    }
}

// ---------------------------------------------------------------------------
// spmm_h: fp16 gather rows, fp32 accumulate on top of fp16 AGG (RMW).
// Unrolled by 4: 4 independent 16B loads in flight per lane.
// ---------------------------------------------------------------------------
template<int FOUT>
__global__ __launch_bounds__(256)
void spmm_h(const __half* __restrict__ H, const int* __restrict__ rowptr,
            const unsigned int* __restrict__ packed, __half* __restrict__ AGGh)
{
    constexpr int T = FOUT / 8;
    int tid = threadIdx.x;
    int local = tid / T;
    int q = tid % T;
    int n = blockIdx.x * (256 / T) + local;
    if (n >= N_NODES) return;
    int r0 = rowptr[n], r1 = rowptr[n + 1];
    __half* ap = AGGh + (size_t)n * FOUT + q * 8;
    float4 acc0, acc1;
    {
        uint4 raw = *(const uint4*)ap;
        const __half2* hp = (const __half2*)&raw;
        float2 f0 = __half22float2(hp[0]);
        float2 f1 = __half22float2(hp[1]);
        float2 f2 = __half22float2(hp[2]);
        float2 f3 = __half22float2(hp[3]);
        acc0 = make_float4(f0.x, f0.y, f1.x, f1.y);
        acc1 = make_float4(f2.x, f2.y, f3.x, f3.y);
    }
    int j = r0;
    for (; j + 3 < r1; j += 4) {
        unsigned int ra = packed[j],     rb = packed[j + 1];
        unsigned int rc = packed[j + 2], rd = packed[j + 3];
        uint4 rawa = *(const uint4*)(H + (size_t)(ra & 0xFFFF) * FOUT + q * 8);
        uint4 rawb = *(const uint4*)(H + (size_t)(rb & 0xFFFF) * FOUT + q * 8);
        uint4 rawc = *(const uint4*)(H + (size_t)(rc & 0xFFFF) * FOUT + q * 8);
        uint4 rawd = *(const uint4*)(H + (size_t)(rd & 0xFFFF) * FOUT + q * 8);
        float wa = __half2float(__ushort_as_half((unsigned short)(ra >> 16)));
        float wb = __half2float(__ushort_as_half((unsigned short)(rb >> 16)));
        float wc = __half2float(__ushort_as_half((unsigned short)(rc >> 16)));
        float wd = __half2float(__ushort_as_half((unsigned short)(rd >> 16)));
        fma8h(acc0, acc1, wa, rawa);
        fma8h(acc0, acc1, wb, rawb);
        fma8h(acc0, acc1, wc, rawc);
        fma8h(acc0, acc1, wd, rawd);
    }
    for (; j < r1; ++j) {
        unsigned int r = packed[j];
        uint4 raw = *(const uint4*)(H + (size_t)(r & 0xFFFF) * FOUT + q * 8);
        float w = __half2float(__ushort_as_half((unsigned short)(r >> 16)));
        fma8h(acc0, acc1, w, raw);
    }
    __half2 hb[4];
    hb[0] = __float22half2_rn(make_float2(acc0.x, acc0.y));
    hb[1] = __float22half2_rn(make_float2(acc0.z, acc0.w));
    hb[2] = __float22half2_rn(make_float2(acc1.x, acc1.y));
    hb[3] = __float22half2_rn(make_float2(acc1.z, acc1.w));
    *(uint4*)ap = *(uint4*)&hb[0];
}

// ---------------------------------------------------------------------------
// pool + head fused: one block/graph; mean of relu(h3h fp16), softmax(p@wd+bd).
// ---------------------------------------------------------------------------
__global__ __launch_bounds__(256)
void pool_kernel(const __half* __restrict__ H, const int* __restrict__ start,
                 const float* __restrict__ WD, const float* __restrict__ BD,
                 float* __restrict__ OUT)
{
    __shared__ float red[8][33];
    int g = blockIdx.x;
    int s = start[g], e = start[g + 1];
    int q = threadIdx.x & 31;
    int lane = threadIdx.x >> 5;
    float acc = 0.f;
    for (int n = s + lane; n < e; n += 8)
        acc += fmaxf(__half2float(H[(size_t)n * 32 + q]), 0.f);
    red[lane][q] = acc;
    __syncthreads();
    if (threadIdx.x < 32) {
        float v = 0.f;
        #pragma unroll
        for (int i = 0; i < 8; ++i) v += red[i][q];
        float inv = (e > s) ? 1.0f / (float)(e - s) : 1.0f;
        float p = v * inv;
        float p0 = p * WD[q * 2 + 0];
        float p1 = p * WD[q * 2 + 1];
        #pragma unroll
        for (int off = 16; off; off >>= 1) {
            p0 += __shfl_down(p0, off, 32);
            p1 += __shfl_down(p1, off, 32);
        }
        if (q == 0) {
            float l0 = p0 + BD[0], l1 = p1 + BD[1];
            float m = fmaxf(l0, l1);
            float e0 = expf(l0 - m), e1 = expf(l1 - m);
            float si = 1.0f / (e0 + e1);
            OUT[g * 2 + 0] = e0 * si;
            OUT[g * 2 + 1] = e1 * si;
        }
    }
}

extern "C" void kernel_launch(void* const* d_in, const int* in_sizes, int n_in,
                              void* d_out, int out_size, void* d_ws, size_t ws_size,
                              hipStream_t stream)
{
    const float* x    = (const float*)d_in[0];
    const float* ew   = (const float*)d_in[1];
    const int*   er   = (const int*)d_in[2];
    const int*   ec   = (const int*)d_in[3];
    const int*   seg  = (const int*)d_in[4];
    const float* w1_1 = (const float*)d_in[5];
    const float* w2_1 = (const float*)d_in[6];
    const float* b_1  = (const float*)d_in[7];
    const float* w1_2 = (const float*)d_in[8];
    const float* w2_2 = (const float*)d_in[9];
    const float* b_2  = (const float*)d_in[10];
    const float* w1_3 = (const float*)d_in[11];
    const float* w2_3 = (const float*)d_in[12];
    const float* b_3  = (const float*)d_in[13];
    const float* wd   = (const float*)d_in[14];
    const float* bd   = (const float*)d_in[15];

    float* ws = (float*)d_ws;
    int*   IW = (int*)d_ws;
    // Fully disjoint workspace — no aliasing hazards.
    __half* XPh    = (__half*)ws;                   // N x 32 fp16
    __half* CIa    = (__half*)(ws + 800000);        // N x 32 fp16
    unsigned int* tmp_sd = (unsigned int*)(ws + 1600000);  // E x 4B
    __half* tmp_w  = (__half*)(ws + 2400000);       // E x 2B
    __half* H2h    = (__half*)(ws + 3200000);       // N x 64 fp16
    __half* A2h    = (__half*)(ws + 4800000);       // N x 64 fp16
    __half* H3h    = (__half*)(ws + 6400000);       // N x 32 fp16
    __half* B2h    = (__half*)(ws + 7200000);       // N x 32 fp16
    unsigned int* packed = (unsigned int*)(IW + 8000000);  // E x 4B
    int*    rowptr = IW + 9000000;                  // N+1
    int*    ghist  = IW + 9060000;                  // NCB*256
    int*    bsum   = IW + 9115000;                  // NCB
    int*    start  = IW + 9120000;                  // G+1
    __half* W1f    = (__half*)(ws + 9125000);       // 64x128 f16 frag-packed
    __half* W2f    = (__half*)(ws + 9130000);       // 128x128 f16 frag-packed
    __half* W3f    = (__half*)(ws + 9139000);       // 64x64 f16 frag-packed

    dim3 blk(256);

    // ---- CSR build + prep (4 dispatches; bsort fuses layer-1 aggx) ----
    hist_prep<<<dim3(256 + 6558), blk, 0, stream>>>(er, x, seg, w1_1, w2_1,
                                                    w1_2, w2_2, w1_3, w2_3,
                                                    ghist, XPh, start,
                                                    W1f, W2f, W3f);
    scan1<<<dim3(NCB), blk, 0, stream>>>(ghist, bsum);
    c_scatter<<<dim3(256), blk, 0, stream>>>(er, ec, ew, ghist, bsum, tmp_sd, tmp_w);
    bsort_aggx<<<dim3(NCB), dim3(512), 0, stream>>>(tmp_sd, tmp_w, bsum, XPh,
                                                    packed, rowptr, CIa);

    // Layers 1+2 fused dense on MFMA
    dense12_mfma<<<dim3(MBLK), blk, 0, stream>>>(CIa, XPh, W1f, b_1,
                                                 W2f, b_2, H2h, A2h);
    spmm_h<64><<<dim3((N_NODES + 31) / 32), blk, 0, stream>>>(H2h, rowptr, packed, A2h);
    // Layer 3 on MFMA
    dense3_mfma<<<dim3(MBLK), blk, 0, stream>>>(A2h, W3f, b_3, H3h, B2h);
    spmm_h<32><<<dim3(MBLK), blk, 0, stream>>>(H3h, rowptr, packed, B2h);

    // Pool + head (fused, atomic-free)
    pool_kernel<<<dim3(N_GRAPHS), blk, 0, stream>>>(B2h, start, wd, bd, (float*)d_out);
}